// Round 12
// baseline (236.746 us; speedup 1.0000x reference)
//
#include <hip/hip_runtime.h>
#include <hip/hip_bf16.h>

// Problem constants (fixed by the reference file).
constexpr int N_NODES = 10000;
constexpr int E_EDGES = 160000;
constexpr int F_IN    = 512;
constexpr int HID     = 1024;
constexpr int NCLS    = 100;
constexpr float NEG_SLOPE = 0.2f;

constexpr int BN = 128, BK = 32;
constexpr int M_PAD = 10112;  // 79*128 = 158*64
constexpr int DEG_CAP = 64;   // Poisson(16)+self: P(>64) ~ 1e-20 on fixed input

typedef __attribute__((ext_vector_type(8))) short bf16x8;  // 8 bf16 (4 VGPRs)
typedef __attribute__((ext_vector_type(4))) float f32x4;
typedef __attribute__((ext_vector_type(2))) float f32x2;   // v_pk_*_f32 pair

__device__ inline void load_lds_16(const void* g, void* l) {
    __builtin_amdgcn_global_load_lds(
        (const __attribute__((address_space(1))) void*)g,
        (__attribute__((address_space(3))) void*)l, 16, 0, 0);
}

__device__ inline float rfl(float x) {
    return __builtin_bit_cast(float,
        __builtin_amdgcn_readfirstlane(__builtin_bit_cast(int, x)));
}

// one dword holding 2 bf16 -> f32 pair (1 VALU op per element: shl / and)
__device__ inline f32x2 bfpair(int d) {
    f32x2 r;
    r.x = __builtin_bit_cast(float, d << 16);
    r.y = __builtin_bit_cast(float, d & (int)0xffff0000);
    return r;
}

// acc quad (4 consecutive n) + bias float4 -> bf16 short4
__device__ inline short4 cvt4(const f32x4 v, const float4 b, int relu) {
    float r0 = v[0] + b.x, r1 = v[1] + b.y, r2 = v[2] + b.z, r3 = v[3] + b.w;
    if (relu) {
        r0 = fmaxf(r0, 0.f); r1 = fmaxf(r1, 0.f);
        r2 = fmaxf(r2, 0.f); r3 = fmaxf(r3, 0.f);
    }
    short4 o;
    o.x = __builtin_bit_cast(short, __float2bfloat16(r0));
    o.y = __builtin_bit_cast(short, __float2bfloat16(r1));
    o.z = __builtin_bit_cast(short, __float2bfloat16(r2));
    o.w = __builtin_bit_cast(short, __float2bfloat16(r3));
    return o;
}

// ---------------------------------------------------------------------------
// 64x128-tile bf16 MFMA GEMM: double-buffered LDS, XOR-swizzled slots,
// swapped-operand epilogue. acc[4][2]=32 regs -> ~80 VGPR -> high occupancy;
// 2x the blocks of the 128-tile version — wins in the latency-bound regime
// (R7/R11 post-mortem: 128-tile gemm1 had MfmaUtil 14%, nothing busy).
// Wave w covers m 0..63, n = w*32..w*32+31.
//   A : [>=M rounded to 64][K] bf16,  Bt : [N][K] bf16 (B transposed)
// ---------------------------------------------------------------------------
__global__ __launch_bounds__(256, 4) void gemm_mfma_64(
    const __hip_bfloat16* __restrict__ A, const __hip_bfloat16* __restrict__ Bt,
    const float* __restrict__ bias, int M, int K, int relu, int n_valid,
    __hip_bfloat16* __restrict__ Cb, int ldb)
{
    __shared__ __align__(16) short As[2][64 * BK];
    __shared__ __align__(16) short Bs[2][BN * BK];

    const int tid  = threadIdx.x;
    const int lane = tid & 63;
    const int w    = tid >> 6;
    const int m0   = blockIdx.y * 64;
    const int n0   = blockIdx.x * BN;

    f32x4 acc[4][2] = {};

    // A tile 64x32 = 256 chunks (1/thread); B tile 128x32 = 512 (2/thread).
    const int ca = tid;
    const int ra = ca >> 2, cca = (ca & 3) ^ ((ra >> 2) & 3);
    const int c0 = tid, c1 = tid + 256;
    const int r0 = c0 >> 2, cc0 = (c0 & 3) ^ ((r0 >> 2) & 3);
    const int r1 = c1 >> 2, cc1 = (c1 & 3) ^ ((r1 >> 2) & 3);

    const short* Ag  = (const short*)A + (size_t)(m0 + ra) * K + cca * 8;
    const short* Bg0 = (const short*)Bt + (size_t)(n0 + r0) * K + cc0 * 8;
    const short* Bg1 = (const short*)Bt + (size_t)(n0 + r1) * K + cc1 * 8;

    const int wn = w * 32;
    const int q  = lane >> 4;
    const int mr = lane & 15;
    const int sl = (q ^ (mr >> 2)) * 8;     // swizzled frag slot

    load_lds_16(Ag,  As[0] + ca * 8);
    load_lds_16(Bg0, Bs[0] + c0 * 8);
    load_lds_16(Bg1, Bs[0] + c1 * 8);

    int cur = 0;
    for (int k0 = 0; k0 < K; k0 += BK) {
        __syncthreads();                 // drains cur-buffer loads (vmcnt)
        const int nxt = cur ^ 1;
        const int kn = k0 + BK;
        if (kn < K) {                    // prefetch next tile AFTER barrier
            load_lds_16(Ag + kn,  As[nxt] + ca * 8);
            load_lds_16(Bg0 + kn, Bs[nxt] + c0 * 8);
            load_lds_16(Bg1 + kn, Bs[nxt] + c1 * 8);
        }

        bf16x8 af[4], bf[2];
        #pragma unroll
        for (int mt = 0; mt < 4; ++mt)
            af[mt] = *(const bf16x8*)&As[cur][(mt * 16 + mr) * BK + sl];
        #pragma unroll
        for (int nt = 0; nt < 2; ++nt)
            bf[nt] = *(const bf16x8*)&Bs[cur][(wn + nt * 16 + mr) * BK + sl];
        #pragma unroll
        for (int mt = 0; mt < 4; ++mt)
            #pragma unroll
            for (int nt = 0; nt < 2; ++nt)
                acc[mt][nt] = __builtin_amdgcn_mfma_f32_16x16x32_bf16(
                    bf[nt], af[mt], acc[mt][nt], 0, 0, 0);   // swapped operands
        cur = nxt;
    }

    // Swapped epilogue: lane mr = m row; regs = 4 consecutive n.
    #pragma unroll
    for (int mt = 0; mt < 4; ++mt) {
        const int gm = m0 + mt * 16 + mr;
        if (gm >= M) continue;
        #pragma unroll
        for (int nt = 0; nt < 2; ++nt) {
            const int gn = n0 + wn + nt * 16 + q * 4;
            if (gn >= n_valid) continue;
            const float4 bv = *(const float4*)&bias[gn];
            short4 o = cvt4(acc[mt][nt], bv, relu);
            *(short4*)((short*)Cb + (size_t)gm * ldb + gn) = o;
        }
    }
}

// ---------------------------------------------------------------------------
// Fused MLP tail, 64-row tiles (grid 158): out = (relu(h1@W2+b2))@Wc+bc.
// ---------------------------------------------------------------------------
constexpr int HS_LD = 136;   // 128 + 8 shorts pad -> 272B rows, 16B aligned

__global__ __launch_bounds__(256) void mlp_tail(
    const __hip_bfloat16* __restrict__ h1, const __hip_bfloat16* __restrict__ W2t,
    const float* __restrict__ b2, const __hip_bfloat16* __restrict__ Wct,
    const float* __restrict__ bc, float* __restrict__ out)
{
    __shared__ __align__(16) short As[2][64 * BK];
    __shared__ __align__(16) short Bs[2][BN * BK];
    __shared__ __align__(16) short Hs[64 * HS_LD];

    const int tid  = threadIdx.x;
    const int lane = tid & 63;
    const int w    = tid >> 6;
    const int m0   = blockIdx.x * 64;

    const int ca = tid;
    const int ra = ca >> 2, cca = (ca & 3) ^ ((ra >> 2) & 3);
    const int c0 = tid, c1 = tid + 256;
    const int r0 = c0 >> 2, cc0 = (c0 & 3) ^ ((r0 >> 2) & 3);
    const int r1 = c1 >> 2, cc1 = (c1 & 3) ^ ((r1 >> 2) & 3);

    const int wn = w * 32;
    const int q  = lane >> 4;
    const int mr = lane & 15;
    const int sl = (q ^ (mr >> 2)) * 8;

    // ---- stage 1: h2 = relu(h1 @ W2 + b2), K=512, double-buffered ----
    {
        f32x4 acc[4][2] = {};
        const short* Ag  = (const short*)h1 + (size_t)(m0 + ra) * 512 + cca * 8;
        const short* Bg0 = (const short*)W2t + (size_t)r0 * 512 + cc0 * 8;
        const short* Bg1 = (const short*)W2t + (size_t)r1 * 512 + cc1 * 8;

        load_lds_16(Ag,  As[0] + ca * 8);
        load_lds_16(Bg0, Bs[0] + c0 * 8);
        load_lds_16(Bg1, Bs[0] + c1 * 8);

        int cur = 0;
        for (int k0 = 0; k0 < 512; k0 += BK) {
            __syncthreads();
            const int nxt = cur ^ 1;
            const int kn = k0 + BK;
            if (kn < 512) {
                load_lds_16(Ag + kn,  As[nxt] + ca * 8);
                load_lds_16(Bg0 + kn, Bs[nxt] + c0 * 8);
                load_lds_16(Bg1 + kn, Bs[nxt] + c1 * 8);
            }
            bf16x8 af[4], bf[2];
            #pragma unroll
            for (int mt = 0; mt < 4; ++mt)
                af[mt] = *(const bf16x8*)&As[cur][(mt * 16 + mr) * BK + sl];
            #pragma unroll
            for (int nt = 0; nt < 2; ++nt)
                bf[nt] = *(const bf16x8*)&Bs[cur][(wn + nt * 16 + mr) * BK + sl];
            #pragma unroll
            for (int mt = 0; mt < 4; ++mt)
                #pragma unroll
                for (int nt = 0; nt < 2; ++nt)
                    acc[mt][nt] = __builtin_amdgcn_mfma_f32_16x16x32_bf16(
                        bf[nt], af[mt], acc[mt][nt], 0, 0, 0);
            cur = nxt;
        }
        __syncthreads();
        #pragma unroll
        for (int mt = 0; mt < 4; ++mt) {
            const int ml = mt * 16 + mr;
            #pragma unroll
            for (int nt = 0; nt < 2; ++nt) {
                const int nl = wn + nt * 16 + q * 4;
                const float4 bv = *(const float4*)&b2[nl];
                short4 o = cvt4(acc[mt][nt], bv, 1);
                *(short4*)&Hs[ml * HS_LD + nl] = o;
            }
        }
    }

    // ---- stage 2: out = h2 @ Wc + bc, K=128 ----
    {
        f32x4 acc[4][2] = {};
        const short* Bg0 = (const short*)Wct + (size_t)r0 * 128 + cc0 * 8;
        const short* Bg1 = (const short*)Wct + (size_t)r1 * 128 + cc1 * 8;

        for (int k0 = 0; k0 < 128; k0 += BK) {
            __syncthreads();     // also orders Hs writes before af reads
            load_lds_16(Bg0 + k0, Bs[0] + c0 * 8);
            load_lds_16(Bg1 + k0, Bs[0] + c1 * 8);
            __syncthreads();

            bf16x8 af[4], bf[2];
            #pragma unroll
            for (int mt = 0; mt < 4; ++mt)
                af[mt] = *(const bf16x8*)&Hs[(mt * 16 + mr) * HS_LD + k0 + q * 8];
            #pragma unroll
            for (int nt = 0; nt < 2; ++nt)
                bf[nt] = *(const bf16x8*)&Bs[0][(wn + nt * 16 + mr) * BK + sl];
            #pragma unroll
            for (int mt = 0; mt < 4; ++mt)
                #pragma unroll
                for (int nt = 0; nt < 2; ++nt)
                    acc[mt][nt] = __builtin_amdgcn_mfma_f32_16x16x32_bf16(
                        bf[nt], af[mt], acc[mt][nt], 0, 0, 0);
        }
        #pragma unroll
        for (int mt = 0; mt < 4; ++mt) {
            const int gm = m0 + mt * 16 + mr;
            if (gm >= N_NODES) continue;
            #pragma unroll
            for (int nt = 0; nt < 2; ++nt) {
                const int gn = wn + nt * 16 + q * 4;
                if (gn >= NCLS) continue;          // NCLS=100, gn mult of 4
                const float4 bv = *(const float4*)&bc[gn];
                float4 o;
                o.x = acc[mt][nt][0] + bv.x;
                o.y = acc[mt][nt][1] + bv.y;
                o.z = acc[mt][nt][2] + bv.z;
                o.w = acc[mt][nt][3] + bv.w;
                *(float4*)(out + (size_t)gm * NCLS + gn) = o;
            }
        }
    }
}

// ---------------------------------------------------------------------------
// One fused pack kernel (block-range dispatch): x->bf16 pad, 5 weight
// transposes to bf16 [N][K], bias concat, PLUS bucketed edge scatter.
// Self-loops stored as real bucket entries (last N_NODES scatter threads).
// ---------------------------------------------------------------------------
__device__ void transpose_tile(const float* __restrict__ W,
                               __hip_bfloat16* __restrict__ Wt,
                               int K, int N, int NP, int bx, int by,
                               int tx, int ty, float (*t)[33])
{
    int n0 = bx * 32, k0 = by * 32;
    #pragma unroll
    for (int i = 0; i < 32; i += 8) {
        int k = k0 + ty + i, n = n0 + tx;
        t[ty + i][tx] = (k < K && n < N) ? W[(size_t)k * N + n] : 0.f;
    }
    __syncthreads();
    #pragma unroll
    for (int i = 0; i < 32; i += 8) {
        int n = n0 + ty + i, k = k0 + tx;
        if (n < NP && k < K)
            Wt[(size_t)n * K + k] = __float2bfloat16(t[tx][ty + i]);
    }
}

constexpr int PK_X    = M_PAD * F_IN / 1024;          // 5056 blocks
constexpr int PK_WL   = PK_X + 512;
constexpr int PK_WR   = PK_WL + 512;
constexpr int PK_W1   = PK_WR + 512;
constexpr int PK_W2   = PK_W1 + 64;
constexpr int PK_WC   = PK_W2 + 16;
constexpr int PK_BLR  = PK_WC + 8;
constexpr int PK_EDGE = PK_BLR + (E_EDGES + N_NODES + 255) / 256;

__global__ __launch_bounds__(256) void pack_all(
    const float* __restrict__ x, __hip_bfloat16* __restrict__ xb,
    const float* __restrict__ Wl, const float* __restrict__ Wr,
    __hip_bfloat16* __restrict__ Wlrt,
    const float* __restrict__ W1, __hip_bfloat16* __restrict__ W1t,
    const float* __restrict__ W2, __hip_bfloat16* __restrict__ W2t,
    const float* __restrict__ Wc, __hip_bfloat16* __restrict__ Wct,
    const float* __restrict__ bl, const float* __restrict__ br,
    float* __restrict__ blr,
    const int* __restrict__ ei, int* __restrict__ cnt, int* __restrict__ srcs)
{
    __shared__ float t[32][33];
    const int b = blockIdx.x;
    const int tid = threadIdx.x;
    const int tx = tid & 31, ty = tid >> 5;

    if (b < PK_X) {
        int i = b * 256 + tid;               // quad index
        int row = i >> 7;
        int base = i << 2;
        short4 o;
        if (row < N_NODES) {
            const float4 v = *(const float4*)(x + base);
            o.x = __builtin_bit_cast(short, __float2bfloat16(v.x));
            o.y = __builtin_bit_cast(short, __float2bfloat16(v.y));
            o.z = __builtin_bit_cast(short, __float2bfloat16(v.z));
            o.w = __builtin_bit_cast(short, __float2bfloat16(v.w));
        } else {
            o.x = o.y = o.z = o.w = 0;
        }
        *(short4*)((short*)xb + base) = o;
    } else if (b < PK_WL) {
        int l = b - PK_X;   // 32 x 16
        transpose_tile(Wl, Wlrt, F_IN, HID, HID, l & 31, l >> 5, tx, ty, t);
    } else if (b < PK_WR) {
        int l = b - PK_WL;
        transpose_tile(Wr, Wlrt + (size_t)HID * F_IN, F_IN, HID, HID,
                       l & 31, l >> 5, tx, ty, t);
    } else if (b < PK_W1) {
        int l = b - PK_WR;  // 16 x 32
        transpose_tile(W1, W1t, HID, 512, 512, l & 15, l >> 4, tx, ty, t);
    } else if (b < PK_W2) {
        int l = b - PK_W1;  // 4 x 16
        transpose_tile(W2, W2t, 512, 128, 128, l & 3, l >> 2, tx, ty, t);
    } else if (b < PK_WC) {
        int l = b - PK_W2;  // 4 x 4
        transpose_tile(Wc, Wct, 128, NCLS, 128, l & 3, l >> 2, tx, ty, t);
    } else if (b < PK_BLR) {
        int i = (b - PK_WC) * 256 + tid;
        if (i < HID) blr[i] = bl[i];
        else if (i < 2 * HID) blr[i] = br[i - HID];
    } else {                // bucketed edge scatter; self-loops are real edges
        int e = (b - PK_BLR) * 256 + tid;
        if (e < E_EDGES + N_NODES) {
            int s, d;
            if (e < E_EDGES) { s = ei[e]; d = ei[E_EDGES + e]; }
            else             { s = e - E_EDGES; d = s; }
            int r = atomicAdd(&cnt[d], 1);
            if (r < DEG_CAP) srcs[(size_t)d * DEG_CAP + r] = s;
        }
    }
}

// ---------------------------------------------------------------------------
// Single-pass GATv2, TWO WAVES PER NODE (block = 4 waves = 2 nodes).
// Inner math on f32x2 pairs (v_pk_*_f32). Bucket srcs includes self-loop;
// online softmax in registers; wave-uniform branch; 2-stage pipeline.
// Near its memory floor (152 MB L2-miss @ ~3.2 TB/s) — R11 post-mortem.
// ---------------------------------------------------------------------------
__global__ __launch_bounds__(256) void gat_node(
    const __hip_bfloat16* __restrict__ xlr, const float* __restrict__ att,
    const float* __restrict__ conv_b,
    const int* __restrict__ cnt, const int* __restrict__ srcs,
    __hip_bfloat16* __restrict__ h)
{
    const int tid  = threadIdx.x;
    const int lane = tid & 63;
    const int wave = tid >> 6;
    const int nloc = wave >> 1;        // node slot within block (0..1)
    const int wsub = wave & 1;         // sub-wave within node (0..1)
    const int i    = blockIdx.x * 2 + nloc;   // grid = N_NODES/2 exactly

    __shared__ float O_s[2][16 * 64];  // [node][j*64+lane] : conflict-free
    __shared__ float ml_s[2][2];

    int deg = __builtin_amdgcn_readfirstlane(cnt[i]);
    if (deg > DEG_CAP) deg = DEG_CAP;  // replay-robust clamp
    const int last = deg - 1;          // deg >= 1 (self-loop always present)
    const int* slist = srcs + (size_t)i * DEG_CAP;
    const short* base = (const short*)xlr;

    // register slices as f32 pairs: cols lane*16 + {2k, 2k+1}
    f32x2 xr2[8], att2[8];
    {
        const int4* xri = (const int4*)(base + (size_t)i * 2048 + HID + lane * 16);
        int4 a0 = xri[0], a1 = xri[1];
        xr2[0] = bfpair(a0.x); xr2[1] = bfpair(a0.y);
        xr2[2] = bfpair(a0.z); xr2[3] = bfpair(a0.w);
        xr2[4] = bfpair(a1.x); xr2[5] = bfpair(a1.y);
        xr2[6] = bfpair(a1.z); xr2[7] = bfpair(a1.w);
        const float* ai = att + lane * 16;
        #pragma unroll
        for (int k = 0; k < 8; ++k) {
            att2[k].x = ai[2 * k];
            att2[k].y = ai[2 * k + 1];
        }
    }

    float m_w = -3e38f, l_w = 0.f;
    f32x2 O2[8];
    #pragma unroll
    for (int k = 0; k < 8; ++k) O2[k] = f32x2{0.f, 0.f};

    int pos = wsub;                    // this wave's edges: wsub, wsub+2, ...
    if (pos < deg) {
        int sc = __builtin_amdgcn_readfirstlane(slist[pos]);
        if ((unsigned)sc >= N_NODES) sc = i;       // replay guard
        int sn = __builtin_amdgcn_readfirstlane(
                     slist[pos + 2 <= last ? pos + 2 : last]);
        if ((unsigned)sn >= N_NODES) sn = i;
        const int4* rp = (const int4*)(base + (size_t)sc * 2048 + lane * 16);
        int4 a0 = rp[0], a1 = rp[1];

        for (; pos < deg; pos += 2) {
            // issue next row load (index already resident)
            const int4* np = (const int4*)(base + (size_t)sn * 2048 + lane * 16);
            int4 b0 = np[0], b1 = np[1];
            // issue next-next index load (clamped; consumed next iteration)
            int s2 = slist[pos + 4 <= last ? pos + 4 : last];

            f32x2 xf[8];
            xf[0] = bfpair(a0.x); xf[1] = bfpair(a0.y);
            xf[2] = bfpair(a0.z); xf[3] = bfpair(a0.w);
            xf[4] = bfpair(a1.x); xf[5] = bfpair(a1.y);
            xf[6] = bfpair(a1.z); xf[7] = bfpair(a1.w);

            f32x2 p2 = f32x2{0.f, 0.f};
            #pragma unroll
            for (int k = 0; k < 8; ++k) {
                f32x2 s = xf[k] + xr2[k];              // v_pk_add_f32
                f32x2 t = s * NEG_SLOPE;               // v_pk_mul_f32
                s.x = fmaxf(s.x, t.x);                 // no pk_max: scalar
                s.y = fmaxf(s.y, t.y);
                p2 = __builtin_elementwise_fma(att2[k], s, p2);  // v_pk_fma
            }
            float p = p2.x + p2.y;
            #pragma unroll
            for (int s = 1; s < 64; s <<= 1) p += __shfl_xor(p, s, 64);
            p = rfl(p);                           // wave-uniform scalar branch

            if (p > m_w) {                        // rare rescale path
                const float scale = __expf(m_w - p);   // 0 on first edge
                const f32x2 sc2 = f32x2{scale, scale};
                l_w = l_w * scale + 1.f;
                #pragma unroll
                for (int k = 0; k < 8; ++k)
                    O2[k] = __builtin_elementwise_fma(sc2, O2[k], xf[k]);
                m_w = p;
            } else {                              // common: 1 exp + 8 pk_fma
                const float alpha = __expf(p - m_w);
                const f32x2 av = f32x2{alpha, alpha};
                l_w += alpha;
                #pragma unroll
                for (int k = 0; k < 8; ++k)
                    O2[k] = __builtin_elementwise_fma(av, xf[k], O2[k]);
            }

            a0 = b0; a1 = b1;
            sn = __builtin_amdgcn_readfirstlane(s2);
            if ((unsigned)sn >= N_NODES) sn = i;
        }
    }

    // one-way exchange: odd sub-wave publishes, even sub-wave combines.
    if (wsub == 1) {
        #pragma unroll
        for (int k = 0; k < 8; ++k) {
            O_s[nloc][(2 * k) * 64 + lane]     = O2[k].x;
            O_s[nloc][(2 * k + 1) * 64 + lane] = O2[k].y;
        }
        if (lane == 0) { ml_s[nloc][0] = m_w; ml_s[nloc][1] = l_w; }
    }
    __syncthreads();

    if (wsub == 0) {
        const float m1 = ml_s[nloc][0], l1 = ml_s[nloc][1];
        const float M  = fmaxf(m_w, m1);
        const float c0 = __expf(m_w - M);
        const float c1 = __expf(m1 - M);     // 0 if partner wave had no edges
        const float invL = 1.f / (l_w * c0 + l1 * c1);
        const float* cb = conv_b + lane * 16;
        bf16x8 o0, o1;
        #pragma unroll
        for (int k = 0; k < 8; ++k) {
            float ox = c0 * O2[k].x + c1 * O_s[nloc][(2 * k) * 64 + lane];
            float oy = c0 * O2[k].y + c1 * O_s[nloc][(2 * k + 1) * 64 + lane];
            float rx = fmaxf(__builtin_fmaf(ox, invL, cb[2 * k]), 0.f);
            float ry = fmaxf(__builtin_fmaf(oy, invL, cb[2 * k + 1]), 0.f);
            short sx = __builtin_bit_cast(short, __float2bfloat16(rx));
            short sy = __builtin_bit_cast(short, __float2bfloat16(ry));
            if (k < 4) { o0[2 * k] = sx; o0[2 * k + 1] = sy; }
            else       { o1[2 * (k - 4)] = sx; o1[2 * (k - 4) + 1] = sy; }
        }
        short* hp = (short*)h + (size_t)i * HID + lane * 16;
        *(bf16x8*)hp = o0;
        *(bf16x8*)(hp + 8) = o1;
    }
}

// ---------------------------------------------------------------------------
extern "C" void kernel_launch(void* const* d_in, const int* in_sizes, int n_in,
                              void* d_out, int out_size, void* d_ws, size_t ws_size,
                              hipStream_t stream)
{
    const float* x      = (const float*)d_in[0];
    const int*   ei     = (const int*)d_in[1];
    const float* Wl     = (const float*)d_in[2];
    const float* bl     = (const float*)d_in[3];
    const float* Wr     = (const float*)d_in[4];
    const float* br     = (const float*)d_in[5];
    const float* att    = (const float*)d_in[6];
    const float* conv_b = (const float*)d_in[7];
    const float* W1     = (const float*)d_in[8];
    const float* b1     = (const float*)d_in[9];
    const float* W2     = (const float*)d_in[10];
    const float* b2     = (const float*)d_in[11];
    const float* Wc     = (const float*)d_in[12];
    const float* bc     = (const float*)d_in[13];
    float* out = (float*)d_out;

    // Workspace layout
    char* p = (char*)d_ws;
    __hip_bfloat16* xlr = (__hip_bfloat16*)p; p += (size_t)M_PAD * 2048 * 2;
    __hip_bfloat16* hb  = (__hip_bfloat16*)p; p += (size_t)M_PAD * HID * 2;
    __hip_bfloat16* xb  = (__hip_bfloat16*)p; p += (size_t)M_PAD * F_IN * 2;
    __hip_bfloat16* Wlrt= (__hip_bfloat16*)p; p += (size_t)2 * HID * F_IN * 2;
    __hip_bfloat16* W1t = (__hip_bfloat16*)p; p += (size_t)512 * HID * 2;
    __hip_bfloat16* W2t = (__hip_bfloat16*)p; p += (size_t)128 * 512 * 2;
    __hip_bfloat16* Wct = (__hip_bfloat16*)p; p += (size_t)128 * 128 * 2;
    float* blr = (float*)p;               p += 2 * HID * 4;
    int* cnt  = (int*)p;                  p += N_NODES * 4;
    int* srcs = (int*)p;                  p += (size_t)N_NODES * DEG_CAP * 4;

    __hip_bfloat16* h1 = xb;   // alias: xb dead after fused GEMM

    const dim3 blk(256);

    hipMemsetAsync(cnt, 0, N_NODES * sizeof(int), stream);

    // pack (x, 5 weights, biases) + bucketed edge+self scatter, one dispatch
    pack_all<<<PK_EDGE, blk, 0, stream>>>(x, xb, Wl, Wr, Wlrt, W1, W1t,
                                          W2, W2t, Wc, Wct, bl, br, blr,
                                          ei, cnt, srcs);

    // fused xl|xr GEMM: [M,512] @ [512,2048] -> xlr bf16 (ld 2048).
    // 64x128 tiles: 16 x 158 = 2528 blocks (latency-bound regime wants blocks).
    gemm_mfma_64<<<dim3(2 * HID / BN, M_PAD / 64), blk, 0, stream>>>(
        xb, Wlrt, blr, N_NODES, F_IN, 0, 2 * HID, xlr, 2048);

    // GATv2 conv + relu -> hb (bf16), two waves per node, packed-f32 math
    gat_node<<<N_NODES / 2, blk, 0, stream>>>(xlr, att, conv_b, cnt, srcs, hb);

    // h1 = relu(hb @ W1 + b1)   (64x128 tiles -> 632 blocks)
    gemm_mfma_64<<<dim3(512 / BN, M_PAD / 64), blk, 0, stream>>>(
        hb, W1t, b1, N_NODES, HID, 1, 512, h1, 512);

    // out = relu(h1 @ W2 + b2) @ Wc + bc  (h2 stays in LDS; 64-row tiles)
    mlp_tail<<<M_PAD / 64, blk, 0, stream>>>(h1, W2t, b2, Wct, bc, out);
}

// Round 13
// 232.522 us; speedup vs baseline: 1.0182x; 1.0182x over previous
//
#include <hip/hip_runtime.h>
#include <hip/hip_bf16.h>

// Problem constants (fixed by the reference file).
constexpr int N_NODES = 10000;
constexpr int E_EDGES = 160000;
constexpr int F_IN    = 512;
constexpr int HID     = 1024;
constexpr int NCLS    = 100;
constexpr float NEG_SLOPE = 0.2f;

constexpr int BN = 128;
constexpr int M_PAD = 10112;  // 79*128 = 158*64
constexpr int DEG_CAP = 64;   // Poisson(16)+self: P(>64) ~ 1e-20 on fixed input

typedef __attribute__((ext_vector_type(8))) short bf16x8;  // 8 bf16 (4 VGPRs)
typedef __attribute__((ext_vector_type(4))) float f32x4;
typedef __attribute__((ext_vector_type(2))) float f32x2;   // v_pk_*_f32 pair

__device__ inline void load_lds_16(const void* g, void* l) {
    __builtin_amdgcn_global_load_lds(
        (const __attribute__((address_space(1))) void*)g,
        (__attribute__((address_space(3))) void*)l, 16, 0, 0);
}

__device__ inline float rfl(float x) {
    return __builtin_bit_cast(float,
        __builtin_amdgcn_readfirstlane(__builtin_bit_cast(int, x)));
}

// one dword holding 2 bf16 -> f32 pair (1 VALU op per element: shl / and)
__device__ inline f32x2 bfpair(int d) {
    f32x2 r;
    r.x = __builtin_bit_cast(float, d << 16);
    r.y = __builtin_bit_cast(float, d & (int)0xffff0000);
    return r;
}

// acc quad (4 consecutive n) + bias float4 -> bf16 short4
__device__ inline short4 cvt4(const f32x4 v, const float4 b, int relu) {
    float r0 = v[0] + b.x, r1 = v[1] + b.y, r2 = v[2] + b.z, r3 = v[3] + b.w;
    if (relu) {
        r0 = fmaxf(r0, 0.f); r1 = fmaxf(r1, 0.f);
        r2 = fmaxf(r2, 0.f); r3 = fmaxf(r3, 0.f);
    }
    short4 o;
    o.x = __builtin_bit_cast(short, __float2bfloat16(r0));
    o.y = __builtin_bit_cast(short, __float2bfloat16(r1));
    o.z = __builtin_bit_cast(short, __float2bfloat16(r2));
    o.w = __builtin_bit_cast(short, __float2bfloat16(r3));
    return o;
}

// ---------------------------------------------------------------------------
// 64x128-tile bf16 MFMA GEMM, BK=64: double-buffered LDS, 8-slot XOR swizzle,
// swapped-operand epilogue. BK=64 doubles compute per barrier (~220 cyc) so
// the prefetch-after-barrier loads are fully covered (BK=32's ~110 cyc was
// not — R12 post-mortem). LDS 48 KB -> 3 blocks/CU.
//   A : [>=M rounded to 64][K] bf16,  Bt : [N][K] bf16 (B transposed)
// ---------------------------------------------------------------------------
__global__ __launch_bounds__(256, 3) void gemm_mfma_64(
    const __hip_bfloat16* __restrict__ A, const __hip_bfloat16* __restrict__ Bt,
    const float* __restrict__ bias, int M, int K, int relu, int n_valid,
    __hip_bfloat16* __restrict__ Cb, int ldb)
{
    constexpr int BK = 64;
    __shared__ __align__(16) short As[2][64 * BK];    // 16 KB
    __shared__ __align__(16) short Bs[2][BN * BK];    // 32 KB

    const int tid  = threadIdx.x;
    const int lane = tid & 63;
    const int w    = tid >> 6;
    const int m0   = blockIdx.y * 64;
    const int n0   = blockIdx.x * BN;

    f32x4 acc[4][2] = {};

    // A tile 64x64 shorts = 512 x16B chunks (2/thread);
    // B tile 128x64 = 1024 chunks (4/thread). Chunk c: row=c>>3, pslot=c&7,
    // global slot = pslot ^ (row&7) (XOR swizzle on source; LDS dst linear).
    int ar[2], acs[2];
    #pragma unroll
    for (int j = 0; j < 2; ++j) {
        int c = tid + 256 * j;
        ar[j] = c >> 3;
        acs[j] = ((c & 7) ^ (ar[j] & 7)) * 8;
    }
    int br_[4], bcs[4];
    #pragma unroll
    for (int j = 0; j < 4; ++j) {
        int c = tid + 256 * j;
        br_[j] = c >> 3;
        bcs[j] = ((c & 7) ^ (br_[j] & 7)) * 8;
    }

    const short* Agp[2];
    #pragma unroll
    for (int j = 0; j < 2; ++j)
        Agp[j] = (const short*)A + (size_t)(m0 + ar[j]) * K + acs[j];
    const short* Bgp[4];
    #pragma unroll
    for (int j = 0; j < 4; ++j)
        Bgp[j] = (const short*)Bt + (size_t)(n0 + br_[j]) * K + bcs[j];

    const int wn = w * 32;
    const int q  = lane >> 4;
    const int mr = lane & 15;

    // prologue: tile 0
    #pragma unroll
    for (int j = 0; j < 2; ++j) load_lds_16(Agp[j], As[0] + (tid + 256 * j) * 8);
    #pragma unroll
    for (int j = 0; j < 4; ++j) load_lds_16(Bgp[j], Bs[0] + (tid + 256 * j) * 8);

    int cur = 0;
    for (int k0 = 0; k0 < K; k0 += BK) {
        __syncthreads();                 // drains cur-buffer loads (vmcnt)
        const int nxt = cur ^ 1;
        const int kn = k0 + BK;
        if (kn < K) {                    // prefetch next tile AFTER barrier
            #pragma unroll
            for (int j = 0; j < 2; ++j)
                load_lds_16(Agp[j] + kn, As[nxt] + (tid + 256 * j) * 8);
            #pragma unroll
            for (int j = 0; j < 4; ++j)
                load_lds_16(Bgp[j] + kn, Bs[nxt] + (tid + 256 * j) * 8);
        }

        #pragma unroll
        for (int ks = 0; ks < 2; ++ks) {
            const int sl = ((ks * 4 + q) ^ (mr & 7)) * 8;
            bf16x8 af[4], bf[2];
            #pragma unroll
            for (int mt = 0; mt < 4; ++mt)
                af[mt] = *(const bf16x8*)&As[cur][(mt * 16 + mr) * BK + sl];
            #pragma unroll
            for (int nt = 0; nt < 2; ++nt)
                bf[nt] = *(const bf16x8*)&Bs[cur][(wn + nt * 16 + mr) * BK + sl];
            #pragma unroll
            for (int mt = 0; mt < 4; ++mt)
                #pragma unroll
                for (int nt = 0; nt < 2; ++nt)
                    acc[mt][nt] = __builtin_amdgcn_mfma_f32_16x16x32_bf16(
                        bf[nt], af[mt], acc[mt][nt], 0, 0, 0);  // swapped ops
        }
        cur = nxt;
    }

    // Swapped epilogue: lane mr = m row; regs = 4 consecutive n.
    #pragma unroll
    for (int mt = 0; mt < 4; ++mt) {
        const int gm = m0 + mt * 16 + mr;
        if (gm >= M) continue;
        #pragma unroll
        for (int nt = 0; nt < 2; ++nt) {
            const int gn = n0 + wn + nt * 16 + q * 4;
            if (gn >= n_valid) continue;
            const float4 bv = *(const float4*)&bias[gn];
            short4 o = cvt4(acc[mt][nt], bv, relu);
            *(short4*)((short*)Cb + (size_t)gm * ldb + gn) = o;
        }
    }
}

// ---------------------------------------------------------------------------
// Fused MLP tail, 64-row tiles (grid 158): out = (relu(h1@W2+b2))@Wc+bc.
// Wct (32 KB) is preloaded ONCE into LDS (drains at stage-1's first barrier);
// stage 2 runs barrier-free from LDS (R12: it paid 8 barriers restaging Wct).
// ---------------------------------------------------------------------------
constexpr int HS_LD = 136;   // 128 + 8 shorts pad -> 272B rows, 16B aligned

__global__ __launch_bounds__(256) void mlp_tail(
    const __hip_bfloat16* __restrict__ h1, const __hip_bfloat16* __restrict__ W2t,
    const float* __restrict__ b2, const __hip_bfloat16* __restrict__ Wct,
    const float* __restrict__ bc, float* __restrict__ out)
{
    constexpr int BK = 32;
    __shared__ __align__(16) short As[2][64 * BK];    // 8 KB
    __shared__ __align__(16) short Bs[2][BN * BK];    // 16 KB
    __shared__ __align__(16) short Hs[64 * HS_LD];    // 17 KB
    __shared__ __align__(16) short Cs[128 * 128];     // 32 KB (Wct, swizzled)

    const int tid  = threadIdx.x;
    const int lane = tid & 63;
    const int w    = tid >> 6;
    const int m0   = blockIdx.x * 64;

    const int ca = tid;
    const int ra = ca >> 2, cca = (ca & 3) ^ ((ra >> 2) & 3);
    const int c0 = tid, c1 = tid + 256;
    const int r0 = c0 >> 2, cc0 = (c0 & 3) ^ ((r0 >> 2) & 3);
    const int r1 = c1 >> 2, cc1 = (c1 & 3) ^ ((r1 >> 2) & 3);

    const int wn = w * 32;
    const int q  = lane >> 4;
    const int mr = lane & 15;
    const int sl = (q ^ (mr >> 2)) * 8;

    // ---- Wct preload: 2048 chunks of 16B, 8/thread. Chunk c: row=c>>4,
    //      pslot=c&15, global slot = pslot ^ (row&15). Drains at 1st barrier.
    #pragma unroll
    for (int j = 0; j < 8; ++j) {
        int c = tid + 256 * j;
        int row = c >> 4;
        int gcol = ((c & 15) ^ (row & 15)) * 8;
        load_lds_16((const short*)Wct + (size_t)row * 128 + gcol, Cs + c * 8);
    }

    // ---- stage 1: h2 = relu(h1 @ W2 + b2), K=512, double-buffered ----
    {
        f32x4 acc[4][2] = {};
        const short* Ag  = (const short*)h1 + (size_t)(m0 + ra) * 512 + cca * 8;
        const short* Bg0 = (const short*)W2t + (size_t)r0 * 512 + cc0 * 8;
        const short* Bg1 = (const short*)W2t + (size_t)r1 * 512 + cc1 * 8;

        load_lds_16(Ag,  As[0] + ca * 8);
        load_lds_16(Bg0, Bs[0] + c0 * 8);
        load_lds_16(Bg1, Bs[0] + c1 * 8);

        int cur = 0;
        for (int k0 = 0; k0 < 512; k0 += BK) {
            __syncthreads();
            const int nxt = cur ^ 1;
            const int kn = k0 + BK;
            if (kn < 512) {
                load_lds_16(Ag + kn,  As[nxt] + ca * 8);
                load_lds_16(Bg0 + kn, Bs[nxt] + c0 * 8);
                load_lds_16(Bg1 + kn, Bs[nxt] + c1 * 8);
            }
            bf16x8 af[4], bf[2];
            #pragma unroll
            for (int mt = 0; mt < 4; ++mt)
                af[mt] = *(const bf16x8*)&As[cur][(mt * 16 + mr) * BK + sl];
            #pragma unroll
            for (int nt = 0; nt < 2; ++nt)
                bf[nt] = *(const bf16x8*)&Bs[cur][(wn + nt * 16 + mr) * BK + sl];
            #pragma unroll
            for (int mt = 0; mt < 4; ++mt)
                #pragma unroll
                for (int nt = 0; nt < 2; ++nt)
                    acc[mt][nt] = __builtin_amdgcn_mfma_f32_16x16x32_bf16(
                        bf[nt], af[mt], acc[mt][nt], 0, 0, 0);
            cur = nxt;
        }
        __syncthreads();
        #pragma unroll
        for (int mt = 0; mt < 4; ++mt) {
            const int ml = mt * 16 + mr;
            #pragma unroll
            for (int nt = 0; nt < 2; ++nt) {
                const int nl = wn + nt * 16 + q * 4;
                const float4 bv = *(const float4*)&b2[nl];
                short4 o = cvt4(acc[mt][nt], bv, 1);
                *(short4*)&Hs[ml * HS_LD + nl] = o;
            }
        }
    }

    __syncthreads();   // Hs writes visible to all waves

    // ---- stage 2: out = h2 @ Wc + bc, K=128, LDS-only, barrier-free ----
    {
        f32x4 acc[4][2] = {};
        #pragma unroll
        for (int kc = 0; kc < 4; ++kc) {          // k0 = kc*32
            bf16x8 af[4], bf[2];
            #pragma unroll
            for (int mt = 0; mt < 4; ++mt)
                af[mt] = *(const bf16x8*)&Hs[(mt * 16 + mr) * HS_LD + kc * 32 + q * 8];
            #pragma unroll
            for (int nt = 0; nt < 2; ++nt) {
                const int row = wn + nt * 16 + mr;
                const int phys = ((kc * 4 + q) ^ (mr & 15)) * 8;
                bf[nt] = *(const bf16x8*)&Cs[row * 128 + phys];
            }
            #pragma unroll
            for (int mt = 0; mt < 4; ++mt)
                #pragma unroll
                for (int nt = 0; nt < 2; ++nt)
                    acc[mt][nt] = __builtin_amdgcn_mfma_f32_16x16x32_bf16(
                        bf[nt], af[mt], acc[mt][nt], 0, 0, 0);
        }
        #pragma unroll
        for (int mt = 0; mt < 4; ++mt) {
            const int gm = m0 + mt * 16 + mr;
            if (gm >= N_NODES) continue;
            #pragma unroll
            for (int nt = 0; nt < 2; ++nt) {
                const int gn = wn + nt * 16 + q * 4;
                if (gn >= NCLS) continue;          // NCLS=100, gn mult of 4
                const float4 bv = *(const float4*)&bc[gn];
                float4 o;
                o.x = acc[mt][nt][0] + bv.x;
                o.y = acc[mt][nt][1] + bv.y;
                o.z = acc[mt][nt][2] + bv.z;
                o.w = acc[mt][nt][3] + bv.w;
                *(float4*)(out + (size_t)gm * NCLS + gn) = o;
            }
        }
    }
}

// ---------------------------------------------------------------------------
// One fused pack kernel (block-range dispatch): x->bf16 pad, 5 weight
// transposes to bf16 [N][K], bias concat, PLUS bucketed edge scatter.
// Self-loops stored as real bucket entries (last N_NODES scatter threads).
// ---------------------------------------------------------------------------
__device__ void transpose_tile(const float* __restrict__ W,
                               __hip_bfloat16* __restrict__ Wt,
                               int K, int N, int NP, int bx, int by,
                               int tx, int ty, float (*t)[33])
{
    int n0 = bx * 32, k0 = by * 32;
    #pragma unroll
    for (int i = 0; i < 32; i += 8) {
        int k = k0 + ty + i, n = n0 + tx;
        t[ty + i][tx] = (k < K && n < N) ? W[(size_t)k * N + n] : 0.f;
    }
    __syncthreads();
    #pragma unroll
    for (int i = 0; i < 32; i += 8) {
        int n = n0 + ty + i, k = k0 + tx;
        if (n < NP && k < K)
            Wt[(size_t)n * K + k] = __float2bfloat16(t[tx][ty + i]);
    }
}

constexpr int PK_X    = M_PAD * F_IN / 1024;          // 5056 blocks
constexpr int PK_WL   = PK_X + 512;
constexpr int PK_WR   = PK_WL + 512;
constexpr int PK_W1   = PK_WR + 512;
constexpr int PK_W2   = PK_W1 + 64;
constexpr int PK_WC   = PK_W2 + 16;
constexpr int PK_BLR  = PK_WC + 8;
constexpr int PK_EDGE = PK_BLR + (E_EDGES + N_NODES + 255) / 256;

__global__ __launch_bounds__(256) void pack_all(
    const float* __restrict__ x, __hip_bfloat16* __restrict__ xb,
    const float* __restrict__ Wl, const float* __restrict__ Wr,
    __hip_bfloat16* __restrict__ Wlrt,
    const float* __restrict__ W1, __hip_bfloat16* __restrict__ W1t,
    const float* __restrict__ W2, __hip_bfloat16* __restrict__ W2t,
    const float* __restrict__ Wc, __hip_bfloat16* __restrict__ Wct,
    const float* __restrict__ bl, const float* __restrict__ br,
    float* __restrict__ blr,
    const int* __restrict__ ei, int* __restrict__ cnt, int* __restrict__ srcs)
{
    __shared__ float t[32][33];
    const int b = blockIdx.x;
    const int tid = threadIdx.x;
    const int tx = tid & 31, ty = tid >> 5;

    if (b < PK_X) {
        int i = b * 256 + tid;               // quad index
        int row = i >> 7;
        int base = i << 2;
        short4 o;
        if (row < N_NODES) {
            const float4 v = *(const float4*)(x + base);
            o.x = __builtin_bit_cast(short, __float2bfloat16(v.x));
            o.y = __builtin_bit_cast(short, __float2bfloat16(v.y));
            o.z = __builtin_bit_cast(short, __float2bfloat16(v.z));
            o.w = __builtin_bit_cast(short, __float2bfloat16(v.w));
        } else {
            o.x = o.y = o.z = o.w = 0;
        }
        *(short4*)((short*)xb + base) = o;
    } else if (b < PK_WL) {
        int l = b - PK_X;   // 32 x 16
        transpose_tile(Wl, Wlrt, F_IN, HID, HID, l & 31, l >> 5, tx, ty, t);
    } else if (b < PK_WR) {
        int l = b - PK_WL;
        transpose_tile(Wr, Wlrt + (size_t)HID * F_IN, F_IN, HID, HID,
                       l & 31, l >> 5, tx, ty, t);
    } else if (b < PK_W1) {
        int l = b - PK_WR;  // 16 x 32
        transpose_tile(W1, W1t, HID, 512, 512, l & 15, l >> 4, tx, ty, t);
    } else if (b < PK_W2) {
        int l = b - PK_W1;  // 4 x 16
        transpose_tile(W2, W2t, 512, 128, 128, l & 3, l >> 2, tx, ty, t);
    } else if (b < PK_WC) {
        int l = b - PK_W2;  // 4 x 4
        transpose_tile(Wc, Wct, 128, NCLS, 128, l & 3, l >> 2, tx, ty, t);
    } else if (b < PK_BLR) {
        int i = (b - PK_WC) * 256 + tid;
        if (i < HID) blr[i] = bl[i];
        else if (i < 2 * HID) blr[i] = br[i - HID];
    } else {                // bucketed edge scatter; self-loops are real edges
        int e = (b - PK_BLR) * 256 + tid;
        if (e < E_EDGES + N_NODES) {
            int s, d;
            if (e < E_EDGES) { s = ei[e]; d = ei[E_EDGES + e]; }
            else             { s = e - E_EDGES; d = s; }
            int r = atomicAdd(&cnt[d], 1);
            if (r < DEG_CAP) srcs[(size_t)d * DEG_CAP + r] = s;
        }
    }
}

// ---------------------------------------------------------------------------
// Single-pass GATv2, TWO WAVES PER NODE. EDGE-PAIR ILP: each iteration
// computes two edges' dots and interleaves the two independent 6-stage
// shuffle-reduce chains (2x ILP on the serial critical path — R12: VALUBusy
// 63%, chain-stall bound). Online-softmax updates applied in edge order
// (bitwise-identical to the sequential version). f32x2 packed math.
// ---------------------------------------------------------------------------
__global__ __launch_bounds__(256) void gat_node(
    const __hip_bfloat16* __restrict__ xlr, const float* __restrict__ att,
    const float* __restrict__ conv_b,
    const int* __restrict__ cnt, const int* __restrict__ srcs,
    __hip_bfloat16* __restrict__ h)
{
    const int tid  = threadIdx.x;
    const int lane = tid & 63;
    const int wave = tid >> 6;
    const int nloc = wave >> 1;        // node slot within block (0..1)
    const int wsub = wave & 1;         // sub-wave within node (0..1)
    const int i    = blockIdx.x * 2 + nloc;   // grid = N_NODES/2 exactly

    __shared__ float O_s[2][16 * 64];  // [node][j*64+lane] : conflict-free
    __shared__ float ml_s[2][2];

    int deg = __builtin_amdgcn_readfirstlane(cnt[i]);
    if (deg > DEG_CAP) deg = DEG_CAP;  // replay-robust clamp
    const int* slist = srcs + (size_t)i * DEG_CAP;
    const short* base = (const short*)xlr;

    // register slices as f32 pairs: cols lane*16 + {2k, 2k+1}
    f32x2 xr2[8], att2[8];
    {
        const int4* xri = (const int4*)(base + (size_t)i * 2048 + HID + lane * 16);
        int4 a0 = xri[0], a1 = xri[1];
        xr2[0] = bfpair(a0.x); xr2[1] = bfpair(a0.y);
        xr2[2] = bfpair(a0.z); xr2[3] = bfpair(a0.w);
        xr2[4] = bfpair(a1.x); xr2[5] = bfpair(a1.y);
        xr2[6] = bfpair(a1.z); xr2[7] = bfpair(a1.w);
        const float* ai = att + lane * 16;
        #pragma unroll
        for (int k = 0; k < 8; ++k) {
            att2[k].x = ai[2 * k];
            att2[k].y = ai[2 * k + 1];
        }
    }

    float m_w = -3e38f, l_w = 0.f;
    f32x2 O2[8];
    #pragma unroll
    for (int k = 0; k < 8; ++k) O2[k] = f32x2{0.f, 0.f};

    // this wave's edges: wsub, wsub+2, ... ; nw = count
    const int nw = (deg - wsub + 1) >> 1;       // <=0 if no edges
    const int lastt = nw - 1;

    // helpers as macros to keep register use tight
#define EIDX(t) (wsub + 2 * ((t) < lastt ? (t) : lastt))
#define GUARD(s) { if ((unsigned)(s) >= N_NODES) (s) = i; }
#define CVT8(dst, v0, v1)                                                   \
    dst[0] = bfpair(v0.x); dst[1] = bfpair(v0.y);                           \
    dst[2] = bfpair(v0.z); dst[3] = bfpair(v0.w);                           \
    dst[4] = bfpair(v1.x); dst[5] = bfpair(v1.y);                           \
    dst[6] = bfpair(v1.z); dst[7] = bfpair(v1.w);
#define DOT(p2, xf)                                                         \
    {                                                                       \
        p2 = f32x2{0.f, 0.f};                                               \
        _Pragma("unroll")                                                   \
        for (int k = 0; k < 8; ++k) {                                       \
            f32x2 s = xf[k] + xr2[k];                                       \
            f32x2 u = s * NEG_SLOPE;                                        \
            s.x = fmaxf(s.x, u.x);                                          \
            s.y = fmaxf(s.y, u.y);                                          \
            p2 = __builtin_elementwise_fma(att2[k], s, p2);                 \
        }                                                                   \
    }
#define UPDATE(p, xf)                                                       \
    {                                                                       \
        if ((p) > m_w) {                                                    \
            const float scale = __expf(m_w - (p));                          \
            const f32x2 sc2 = f32x2{scale, scale};                          \
            l_w = l_w * scale + 1.f;                                        \
            _Pragma("unroll")                                               \
            for (int k = 0; k < 8; ++k)                                     \
                O2[k] = __builtin_elementwise_fma(sc2, O2[k], xf[k]);       \
            m_w = (p);                                                      \
        } else {                                                            \
            const float alpha = __expf((p)-m_w);                            \
            const f32x2 av = f32x2{alpha, alpha};                           \
            l_w += alpha;                                                   \
            _Pragma("unroll")                                               \
            for (int k = 0; k < 8; ++k)                                     \
                O2[k] = __builtin_elementwise_fma(av, xf[k], O2[k]);        \
        }                                                                   \
    }

    if (nw > 0) {
        int sA = __builtin_amdgcn_readfirstlane(slist[EIDX(0)]); GUARD(sA);
        int sC = __builtin_amdgcn_readfirstlane(slist[EIDX(1)]); GUARD(sC);
        const int4* ap = (const int4*)(base + (size_t)sA * 2048 + lane * 16);
        const int4* cp = (const int4*)(base + (size_t)sC * 2048 + lane * 16);
        int4 A0 = ap[0], A1 = ap[1];
        int4 C0 = cp[0], C1 = cp[1];
        int pA = slist[EIDX(2)];          // index prefetch (vector load)
        int pC = slist[EIDX(3)];

        int t = 0;
        for (; t + 1 < nw; t += 2) {
            int snA = __builtin_amdgcn_readfirstlane(pA); GUARD(snA);
            int snC = __builtin_amdgcn_readfirstlane(pC); GUARD(snC);
            const int4* bp = (const int4*)(base + (size_t)snA * 2048 + lane * 16);
            const int4* dp = (const int4*)(base + (size_t)snC * 2048 + lane * 16);
            int4 B0 = bp[0], B1 = bp[1];
            int4 D0 = dp[0], D1 = dp[1];
            pA = slist[EIDX(t + 4)];
            pC = slist[EIDX(t + 5)];

            f32x2 xfA[8], xfC[8];
            CVT8(xfA, A0, A1);
            CVT8(xfC, C0, C1);

            f32x2 p2a, p2c;
            DOT(p2a, xfA);
            DOT(p2c, xfC);
            float pa = p2a.x + p2a.y;
            float pc = p2c.x + p2c.y;
            #pragma unroll
            for (int s = 1; s < 64; s <<= 1) {   // two independent chains
                pa += __shfl_xor(pa, s, 64);
                pc += __shfl_xor(pc, s, 64);
            }
            pa = rfl(pa);
            pc = rfl(pc);

            UPDATE(pa, xfA);                     // edge t, then edge t+1
            UPDATE(pc, xfC);

            A0 = B0; A1 = B1; C0 = D0; C1 = D1;
        }
        if (t < nw) {                            // leftover single edge in A
            f32x2 xfA[8];
            CVT8(xfA, A0, A1);
            f32x2 p2a;
            DOT(p2a, xfA);
            float pa = p2a.x + p2a.y;
            #pragma unroll
            for (int s = 1; s < 64; s <<= 1) pa += __shfl_xor(pa, s, 64);
            pa = rfl(pa);
            UPDATE(pa, xfA);
        }
    }
#undef EIDX
#undef GUARD
#undef CVT8
#undef DOT
#undef UPDATE

    // one-way exchange: odd sub-wave publishes, even sub-wave combines.
    if (wsub == 1) {
        #pragma unroll
        for (int k = 0; k < 8; ++k) {
            O_s[nloc][(2 * k) * 64 + lane]     = O2[k].x;
            O_s[nloc][(2 * k + 1) * 64 + lane] = O2[k].y;
        }
        if (lane == 0) { ml_s[nloc][0] = m_w; ml_s[nloc][1] = l_w; }
    }
    __syncthreads();

    if (wsub == 0) {
        const float m1 = ml_s[nloc][0], l1 = ml_s[nloc][1];
        const float M  = fmaxf(m_w, m1);
        const float c0 = __expf(m_w - M);
        const float c1 = __expf(m1 - M);     // 0 if partner wave had no edges
        const float invL = 1.f / (l_w * c0 + l1 * c1);
        const float* cb = conv_b + lane * 16;
        bf16x8 o0, o1;
        #pragma unroll
        for (int k = 0; k < 8; ++k) {
            float ox = c0 * O2[k].x + c1 * O_s[nloc][(2 * k) * 64 + lane];
            float oy = c0 * O2[k].y + c1 * O_s[nloc][(2 * k + 1) * 64 + lane];
            float rx = fmaxf(__builtin_fmaf(ox, invL, cb[2 * k]), 0.f);
            float ry = fmaxf(__builtin_fmaf(oy, invL, cb[2 * k + 1]), 0.f);
            short sx = __builtin_bit_cast(short, __float2bfloat16(rx));
            short sy = __builtin_bit_cast(short, __float2bfloat16(ry));
            if (k < 4) { o0[2 * k] = sx; o0[2 * k + 1] = sy; }
            else       { o1[2 * (k - 4)] = sx; o1[2 * (k - 4) + 1] = sy; }
        }
        short* hp = (short*)h + (size_t)i * HID + lane * 16;
        *(bf16x8*)hp = o0;
        *(bf16x8*)(hp + 8) = o1;
    }
}

// ---------------------------------------------------------------------------
extern "C" void kernel_launch(void* const* d_in, const int* in_sizes, int n_in,
                              void* d_out, int out_size, void* d_ws, size_t ws_size,
                              hipStream_t stream)
{
    const float* x      = (const float*)d_in[0];
    const int*   ei     = (const int*)d_in[1];
    const float* Wl     = (const float*)d_in[2];
    const float* bl     = (const float*)d_in[3];
    const float* Wr     = (const float*)d_in[4];
    const float* br     = (const float*)d_in[5];
    const float* att    = (const float*)d_in[6];
    const float* conv_b = (const float*)d_in[7];
    const float* W1     = (const float*)d_in[8];
    const float* b1     = (const float*)d_in[9];
    const float* W2     = (const float*)d_in[10];
    const float* b2     = (const float*)d_in[11];
    const float* Wc     = (const float*)d_in[12];
    const float* bc     = (const float*)d_in[13];
    float* out = (float*)d_out;

    // Workspace layout
    char* p = (char*)d_ws;
    __hip_bfloat16* xlr = (__hip_bfloat16*)p; p += (size_t)M_PAD * 2048 * 2;
    __hip_bfloat16* hb  = (__hip_bfloat16*)p; p += (size_t)M_PAD * HID * 2;
    __hip_bfloat16* xb  = (__hip_bfloat16*)p; p += (size_t)M_PAD * F_IN * 2;
    __hip_bfloat16* Wlrt= (__hip_bfloat16*)p; p += (size_t)2 * HID * F_IN * 2;
    __hip_bfloat16* W1t = (__hip_bfloat16*)p; p += (size_t)512 * HID * 2;
    __hip_bfloat16* W2t = (__hip_bfloat16*)p; p += (size_t)128 * 512 * 2;
    __hip_bfloat16* Wct = (__hip_bfloat16*)p; p += (size_t)128 * 128 * 2;
    float* blr = (float*)p;               p += 2 * HID * 4;
    int* cnt  = (int*)p;                  p += N_NODES * 4;
    int* srcs = (int*)p;                  p += (size_t)N_NODES * DEG_CAP * 4;

    __hip_bfloat16* h1 = xb;   // alias: xb dead after fused GEMM

    const dim3 blk(256);

    hipMemsetAsync(cnt, 0, N_NODES * sizeof(int), stream);

    // pack (x, 5 weights, biases) + bucketed edge+self scatter, one dispatch
    pack_all<<<PK_EDGE, blk, 0, stream>>>(x, xb, Wl, Wr, Wlrt, W1, W1t,
                                          W2, W2t, Wc, Wct, bl, br, blr,
                                          ei, cnt, srcs);

    // fused xl|xr GEMM: [M,512] @ [512,2048] -> xlr bf16 (ld 2048). BK=64.
    gemm_mfma_64<<<dim3(2 * HID / BN, M_PAD / 64), blk, 0, stream>>>(
        xb, Wlrt, blr, N_NODES, F_IN, 0, 2 * HID, xlr, 2048);

    // GATv2 conv + relu -> hb (bf16): 2 waves/node, edge-pair ILP
    gat_node<<<N_NODES / 2, blk, 0, stream>>>(xlr, att, conv_b, cnt, srcs, hb);

    // h1 = relu(hb @ W1 + b1)   (64x128 tiles, BK=64)
    gemm_mfma_64<<<dim3(512 / BN, M_PAD / 64), blk, 0, stream>>>(
        hb, W1t, b1, N_NODES, HID, 1, 512, h1, 512);

    // out = relu(h1 @ W2 + b2) @ Wc + bc  (h2 + Wc stay in LDS)
    mlp_tail<<<M_PAD / 64, blk, 0, stream>>>(h1, W2t, b2, Wct, bc, out);
}